// Round 3
// baseline (332.844 us; speedup 1.0000x reference)
//
#include <hip/hip_runtime.h>

#define NB    384            // 6 waves; 1152 = 384*3
#define ROWS  3
#define N_ROUTE 1152
#define C_IN  8
#define C_OUT 16

// P fully register-resident: 3 rows x 16 = 48 VGPRs/thread. No LDS on the
// critical path; LDS only holds the cross-wave reduction scratch.
// launch_bounds(384,2): VGPR cap 256 -> compiler free to keep P in regs
// (R2's (384,4) forced VGPR=64 and spilled P to scratch: 61 MB WRITE_SIZE).
__global__ __launch_bounds__(NB, 2)
void capsule_routing(const float* __restrict__ x,
                     const float* __restrict__ W,
                     float* __restrict__ out)
{
    // double-buffered reduction scratch: [buf][wave][16 s-partials + Z], padded to 20
    __shared__ float red[2][6][20];

    const int t    = threadIdx.x;
    const int bid  = blockIdx.x;
    const int c    = bid >> 8;
    const int b    = bid & 255;
    const int lane = t & 63;
    const int wid  = t >> 6;

    float p[ROWS][16];   // priors for owned rows n = t + 384k  (static idx only)

    // ---------------- Phase A: priors, fully per-thread ----------------
    {
        const float* __restrict__ xb = x + (size_t)b * (N_ROUTE * C_IN);
        const float* __restrict__ Wc = W + (size_t)c * (N_ROUTE * C_IN * C_OUT);
        #pragma unroll
        for (int k = 0; k < ROWS; ++k) {
            const int n = t + k * NB;
            const float4 x0 = *reinterpret_cast<const float4*>(xb + n * C_IN);
            const float4 x1 = *reinterpret_cast<const float4*>(xb + n * C_IN + 4);
            const float xs[8] = {x0.x, x0.y, x0.z, x0.w, x1.x, x1.y, x1.z, x1.w};
            const float4* __restrict__ wp =
                reinterpret_cast<const float4*>(Wc + (size_t)n * (C_IN * C_OUT));
            #pragma unroll
            for (int o = 0; o < 16; ++o) p[k][o] = 0.f;
            #pragma unroll
            for (int i = 0; i < 8; ++i) {
                const float xi = xs[i];
                #pragma unroll
                for (int q = 0; q < 4; ++q) {
                    const float4 w = wp[i * 4 + q];
                    p[k][q * 4 + 0] = fmaf(xi, w.x, p[k][q * 4 + 0]);
                    p[k][q * 4 + 1] = fmaf(xi, w.y, p[k][q * 4 + 1]);
                    p[k][q * 4 + 2] = fmaf(xi, w.z, p[k][q * 4 + 2]);
                    p[k][q * 4 + 3] = fmaf(xi, w.w, p[k][q * 4 + 3]);
                }
            }
        }
    }
    // No barrier needed: each thread computed its own P rows.

    float lg[ROWS] = {0.f, 0.f, 0.f};
    float vcur[16];

    #pragma unroll
    for (int it = 0; it < 3; ++it) {
        // e[n] = exp(logit[n]); no max-subtraction needed:
        // |logit| <= 2*||P_row|| (Cauchy-Schwarz, ||v||<1) << 88.
        float ek[ROWS];
        float zp;
        if (it == 0) {
            ek[0] = ek[1] = ek[2] = 1.f;
            zp = 3.f;                       // softmax of zeros = uniform
        } else {
            zp = 0.f;
            #pragma unroll
            for (int k = 0; k < ROWS; ++k) { ek[k] = __expf(lg[k]); zp += ek[k]; }
        }

        // per-thread partial s[o] = sum_k e_k * P[k][o]
        float sp[16];
        #pragma unroll
        for (int o = 0; o < 16; ++o) sp[o] = 0.f;
        #pragma unroll
        for (int k = 0; k < ROWS; ++k) {
            const float e = ek[k];
            #pragma unroll
            for (int o = 0; o < 16; ++o) sp[o] = fmaf(e, p[k][o], sp[o]);
        }

        // fused 17-value butterfly reduce (16 s-partials + Z) across the wave
        #pragma unroll
        for (int off = 32; off >= 1; off >>= 1) {
            #pragma unroll
            for (int o = 0; o < 16; ++o) sp[o] += __shfl_xor(sp[o], off);
            zp += __shfl_xor(zp, off);
        }

        float (*rb)[20] = red[it & 1];
        if (lane == 0) {
            #pragma unroll
            for (int o = 0; o < 16; ++o) rb[wid][o] = sp[o];
            rb[wid][16] = zp;
        }
        __syncthreads();                    // the only barrier per iteration

        float s[16];
        #pragma unroll
        for (int o = 0; o < 16; ++o) s[o] = 0.f;
        float Z = 0.f;
        #pragma unroll
        for (int w2 = 0; w2 < 6; ++w2) {    // broadcast reads: conflict-free
            #pragma unroll
            for (int o = 0; o < 16; ++o) s[o] += rb[w2][o];
            Z += rb[w2][16];
        }

        const float Zinv = 1.f / Z;
        float sq = 0.f;
        #pragma unroll
        for (int o = 0; o < 16; ++o) { s[o] *= Zinv; sq = fmaf(s[o], s[o], sq); }
        const float fac = sqrtf(sq) / (1.f + sq);   // squash factor
        #pragma unroll
        for (int o = 0; o < 16; ++o) vcur[o] = s[o] * fac;

        if (it < 2) {
            // logit[n] += dot(P[n], v)   (scalar per n — Co-independent)
            #pragma unroll
            for (int k = 0; k < ROWS; ++k) {
                float d = 0.f;
                #pragma unroll
                for (int o = 0; o < 16; ++o) d = fmaf(p[k][o], vcur[o], d);
                lg[k] += d;
            }
        }
    }

    if (t < 16) out[((size_t)bid << 4) + t] = vcur[t];
}

extern "C" void kernel_launch(void* const* d_in, const int* in_sizes, int n_in,
                              void* d_out, int out_size, void* d_ws, size_t ws_size,
                              hipStream_t stream)
{
    const float* x   = (const float*)d_in[0];
    const float* W   = (const float*)d_in[1];
    float*       out = (float*)d_out;
    capsule_routing<<<dim3(10 * 256), dim3(NB), 0, stream>>>(x, W, out);
}

// Round 4
// 255.157 us; speedup vs baseline: 1.3045x; 1.3045x over previous
//
#include <hip/hip_runtime.h>

#define NB     384           // 6 waves; 1152 = 384*3
#define ROWS   3
#define N_ROUTE 1152
#define C_IN   8
#define C_OUT  16
#define PAD    17            // LDS row stride; gcd(17,32)=1 -> fill reads conflict-free
#define NPASS  12            // 1152 rows / 96 rows-per-pass

// Phase A: coalesced (4 threads per n-row, each owns 4 outputs) -> P in LDS.
// Then one-time LDS->register fill (3 rows x 16 per thread), and all 3 routing
// iterations run register-resident: 1 barrier per iteration, LDS only for the
// 17-value cross-wave reduction scratch.
__global__ __launch_bounds__(NB, 2)
void capsule_routing(const float* __restrict__ x,
                     const float* __restrict__ W,
                     float* __restrict__ out)
{
    __shared__ float P[N_ROUTE * PAD];     // 78336 B
    __shared__ float red[2][6][20];        // 960 B reduction scratch

    const int t    = threadIdx.x;
    const int bid  = blockIdx.x;
    const int c    = bid >> 8;
    const int b    = bid & 255;
    const int lane = t & 63;
    const int wid  = t >> 6;

    // ---------------- Phase A: coalesced priors into LDS ----------------
    {
        const int og = t & 3;              // o-quad: o = og*4 .. og*4+3
        const int nl = t >> 2;             // 0..95
        const float* __restrict__ xb = x + (size_t)b * (N_ROUTE * C_IN);
        const float* __restrict__ Wc = W + (size_t)c * (N_ROUTE * C_IN * C_OUT);
        #pragma unroll 2
        for (int pp = 0; pp < NPASS; ++pp) {
            const int n = pp * 96 + nl;
            const float4 x0 = *reinterpret_cast<const float4*>(xb + n * C_IN);
            const float4 x1 = *reinterpret_cast<const float4*>(xb + n * C_IN + 4);
            const float xs[8] = {x0.x, x0.y, x0.z, x0.w, x1.x, x1.y, x1.z, x1.w};
            // wave reads 16 consecutive rows x 64B -> fully coalesced lines
            const float* __restrict__ wp = Wc + (size_t)n * (C_IN * C_OUT) + (og << 2);
            float4 acc = make_float4(0.f, 0.f, 0.f, 0.f);
            #pragma unroll
            for (int i = 0; i < 8; ++i) {
                const float4 w = *reinterpret_cast<const float4*>(wp + i * C_OUT);
                acc.x = fmaf(xs[i], w.x, acc.x);
                acc.y = fmaf(xs[i], w.y, acc.y);
                acc.z = fmaf(xs[i], w.z, acc.z);
                acc.w = fmaf(xs[i], w.w, acc.w);
            }
            const int base = n * PAD + (og << 2);
            P[base + 0] = acc.x;
            P[base + 1] = acc.y;
            P[base + 2] = acc.z;
            P[base + 3] = acc.w;
        }
    }
    __syncthreads();

    // ---------------- One-time register fill: 3 rows x 16 per thread ----------------
    float p[ROWS][16];
    #pragma unroll
    for (int k = 0; k < ROWS; ++k) {
        const int base = (t + k * NB) * PAD;   // banks spread: gcd(17,32)=1
        #pragma unroll
        for (int o = 0; o < 16; ++o) p[k][o] = P[base + o];
    }
    // No barrier needed: P is read-only from here on.

    float lg[ROWS] = {0.f, 0.f, 0.f};
    float vcur[16];

    #pragma unroll
    for (int it = 0; it < 3; ++it) {
        // e[n] = exp(logit[n]); max-subtraction unnecessary:
        // |logit| <= 2*||P_row|| (Cauchy-Schwarz, ||v||<1) << 88.
        float ek[ROWS];
        float zp;
        if (it == 0) {
            ek[0] = ek[1] = ek[2] = 1.f;
            zp = 3.f;                          // softmax of zeros = uniform
        } else {
            zp = 0.f;
            #pragma unroll
            for (int k = 0; k < ROWS; ++k) { ek[k] = __expf(lg[k]); zp += ek[k]; }
        }

        // per-thread partial s[o]
        float sp[16];
        #pragma unroll
        for (int o = 0; o < 16; ++o) sp[o] = 0.f;
        #pragma unroll
        for (int k = 0; k < ROWS; ++k) {
            const float e = ek[k];
            #pragma unroll
            for (int o = 0; o < 16; ++o) sp[o] = fmaf(e, p[k][o], sp[o]);
        }

        // fused 17-value wave butterfly (16 s-partials + Z)
        #pragma unroll
        for (int off = 32; off >= 1; off >>= 1) {
            #pragma unroll
            for (int o = 0; o < 16; ++o) sp[o] += __shfl_xor(sp[o], off);
            zp += __shfl_xor(zp, off);
        }

        float (*rb)[20] = red[it & 1];
        if (lane == 0) {
            #pragma unroll
            for (int o = 0; o < 16; ++o) rb[wid][o] = sp[o];
            rb[wid][16] = zp;
        }
        __syncthreads();                       // the only barrier per iteration

        float s[16];
        #pragma unroll
        for (int o = 0; o < 16; ++o) s[o] = 0.f;
        float Z = 0.f;
        #pragma unroll
        for (int w2 = 0; w2 < 6; ++w2) {       // broadcast reads: conflict-free
            #pragma unroll
            for (int o = 0; o < 16; ++o) s[o] += rb[w2][o];
            Z += rb[w2][16];
        }

        const float Zinv = 1.f / Z;
        float sq = 0.f;
        #pragma unroll
        for (int o = 0; o < 16; ++o) { s[o] *= Zinv; sq = fmaf(s[o], s[o], sq); }
        const float fac = sqrtf(sq) / (1.f + sq);   // squash factor
        #pragma unroll
        for (int o = 0; o < 16; ++o) vcur[o] = s[o] * fac;

        if (it < 2) {
            // logit[n] += dot(P[n], v)  (scalar per n — Co-independent)
            #pragma unroll
            for (int k = 0; k < ROWS; ++k) {
                float d = 0.f;
                #pragma unroll
                for (int o = 0; o < 16; ++o) d = fmaf(p[k][o], vcur[o], d);
                lg[k] += d;
            }
        }
    }

    if (t < 16) out[((size_t)bid << 4) + t] = vcur[t];
}

extern "C" void kernel_launch(void* const* d_in, const int* in_sizes, int n_in,
                              void* d_out, int out_size, void* d_ws, size_t ws_size,
                              hipStream_t stream)
{
    const float* x   = (const float*)d_in[0];
    const float* W   = (const float*)d_in[1];
    float*       out = (float*)d_out;
    capsule_routing<<<dim3(10 * 256), dim3(NB), 0, stream>>>(x, W, out);
}

// Round 5
// 136.029 us; speedup vs baseline: 2.4469x; 1.8758x over previous
//
#include <hip/hip_runtime.h>
#include <hip/hip_fp16.h>

#define NB    384            // 6 waves; 1152 = 384*3 -> exactly 3 rows/thread
#define ROWS  3
#define N_ROUTE 1152
#define C_IN  8
#define C_OUT 16
#define RS    9              // P row stride in u32 (8 data + 1 pad); gcd(9,32)=1

// 6-step DPP wave-64 sum; full sum lands in lane 63 (others hold partials).
template<int CTRL>
__device__ __forceinline__ float dpp_add(float v) {
    int t = __builtin_amdgcn_update_dpp(0, __float_as_int(v), CTRL, 0xF, 0xF, true);
    return v + __int_as_float(t);
}
__device__ __forceinline__ float wave_sum63(float v) {
    v = dpp_add<0x111>(v);   // row_shr:1
    v = dpp_add<0x112>(v);   // row_shr:2
    v = dpp_add<0x114>(v);   // row_shr:4
    v = dpp_add<0x118>(v);   // row_shr:8  -> lane 15/31/47/63 = row sums
    v = dpp_add<0x142>(v);   // row_bcast:15
    v = dpp_add<0x143>(v);   // row_bcast:31 -> lane 63 = full sum
    return v;
}

__global__ __launch_bounds__(NB, 2)
void capsule_routing(const float* __restrict__ x,
                     const float* __restrict__ W,
                     float* __restrict__ out)
{
    __shared__ unsigned int P[N_ROUTE * RS];  // fp16x2-packed priors, 41472 B
    __shared__ float red[6][20];              // per-wave partials: 16 s + [16]=Z
    __shared__ float vfin[16];                // broadcast v

    const int t    = threadIdx.x;
    const int bid  = blockIdx.x;
    const int c    = bid >> 8;
    const int b    = bid & 255;
    const int lane = t & 63;
    const int wid  = t >> 6;

    // ---------------- Phase A: coalesced priors -> fp16-packed LDS ----------------
    {
        const int og = t & 3;                 // o-quad
        const int nl = t >> 2;                // 0..95
        const float* __restrict__ xb = x + (size_t)b * (N_ROUTE * C_IN);
        const float* __restrict__ Wc = W + (size_t)c * (N_ROUTE * C_IN * C_OUT);
        #pragma unroll 2
        for (int pp = 0; pp < 12; ++pp) {
            const int n = pp * 96 + nl;
            const float4 x0 = *reinterpret_cast<const float4*>(xb + n * C_IN);
            const float4 x1 = *reinterpret_cast<const float4*>(xb + n * C_IN + 4);
            const float xs[8] = {x0.x, x0.y, x0.z, x0.w, x1.x, x1.y, x1.z, x1.w};
            const float* __restrict__ wp = Wc + (size_t)n * (C_IN * C_OUT) + (og << 2);
            float4 acc = make_float4(0.f, 0.f, 0.f, 0.f);
            #pragma unroll
            for (int i = 0; i < 8; ++i) {
                const float4 w = *reinterpret_cast<const float4*>(wp + i * C_OUT);
                acc.x = fmaf(xs[i], w.x, acc.x);
                acc.y = fmaf(xs[i], w.y, acc.y);
                acc.z = fmaf(xs[i], w.z, acc.z);
                acc.w = fmaf(xs[i], w.w, acc.w);
            }
            __half2 h0 = __floats2half2_rn(acc.x, acc.y);
            __half2 h1 = __floats2half2_rn(acc.z, acc.w);
            const int base = n * RS + (og << 1);
            P[base + 0] = *reinterpret_cast<unsigned int*>(&h0);
            P[base + 1] = *reinterpret_cast<unsigned int*>(&h1);
        }
    }
    __syncthreads();

    // ---------------- Routing: fused single P-pass per iteration ----------------
    float vprev[16];
    #pragma unroll
    for (int o = 0; o < 16; ++o) vprev[o] = 0.f;
    float lg[ROWS] = {0.f, 0.f, 0.f};

    #pragma unroll
    for (int it = 0; it < 3; ++it) {
        float sp[16];
        #pragma unroll
        for (int o = 0; o < 16; ++o) sp[o] = 0.f;
        float zp = 0.f;

        // one pass over owned rows: logit update, exp, weighted accumulation
        #pragma unroll
        for (int k = 0; k < ROWS; ++k) {
            const int n = t + k * NB;
            const unsigned int* __restrict__ pr = &P[n * RS];
            float pv[16];
            #pragma unroll
            for (int j = 0; j < 8; ++j) {
                __half2 h = *reinterpret_cast<const __half2*>(&pr[j]);
                float2 f = __half22float2(h);
                pv[2 * j]     = f.x;
                pv[2 * j + 1] = f.y;
            }
            float d = 0.f;
            #pragma unroll
            for (int o = 0; o < 16; ++o) d = fmaf(pv[o], vprev[o], d);
            lg[k] += d;                        // iter0: vprev=0 -> lg stays 0
            const float e = __expf(lg[k]);     // no max-sub: |lg|<~40, fp32 safe
            zp += e;
            #pragma unroll
            for (int o = 0; o < 16; ++o) sp[o] = fmaf(e, pv[o], sp[o]);
        }

        // 17-value wave reduction on the VALU pipe (DPP), result in lane 63
        #pragma unroll
        for (int o = 0; o < 16; ++o) sp[o] = wave_sum63(sp[o]);
        zp = wave_sum63(zp);
        if (lane == 63) {
            #pragma unroll
            for (int o = 0; o < 16; ++o) red[wid][o] = sp[o];
            red[wid][16] = zp;
        }
        __syncthreads();                       // barrier 1

        // final combine + squash by wave 0, lanes 0..15
        if (t < 16) {
            float tot = 0.f, Zt = 0.f;
            #pragma unroll
            for (int w2 = 0; w2 < 6; ++w2) {
                tot += red[w2][t];
                Zt  += red[w2][16];
            }
            const float so = tot / Zt;         // s[o]
            float sq = so * so;                // 16-lane butterfly for ||s||^2
            #pragma unroll
            for (int off = 8; off >= 1; off >>= 1) sq += __shfl_xor(sq, off);
            const float fac = sqrtf(sq) / (1.f + sq);
            const float vo  = so * fac;
            if (it == 2) out[((size_t)bid << 4) + t] = vo;
            else         vfin[t] = vo;
        }
        if (it < 2) {
            __syncthreads();                   // barrier 2
            const float4 v0 = *reinterpret_cast<const float4*>(&vfin[0]);
            const float4 v1 = *reinterpret_cast<const float4*>(&vfin[4]);
            const float4 v2 = *reinterpret_cast<const float4*>(&vfin[8]);
            const float4 v3 = *reinterpret_cast<const float4*>(&vfin[12]);
            vprev[0]=v0.x;  vprev[1]=v0.y;  vprev[2]=v0.z;  vprev[3]=v0.w;
            vprev[4]=v1.x;  vprev[5]=v1.y;  vprev[6]=v1.z;  vprev[7]=v1.w;
            vprev[8]=v2.x;  vprev[9]=v2.y;  vprev[10]=v2.z; vprev[11]=v2.w;
            vprev[12]=v3.x; vprev[13]=v3.y; vprev[14]=v3.z; vprev[15]=v3.w;
        }
    }
}

extern "C" void kernel_launch(void* const* d_in, const int* in_sizes, int n_in,
                              void* d_out, int out_size, void* d_ws, size_t ws_size,
                              hipStream_t stream)
{
    const float* x   = (const float*)d_in[0];
    const float* W   = (const float*)d_in[1];
    float*       out = (float*)d_out;
    capsule_routing<<<dim3(10 * 256), dim3(NB), 0, stream>>>(x, W, out);
}